// Round 1
// 20744.125 us; speedup vs baseline: 1.2003x; 1.2003x over previous
//
#include <hip/hip_runtime.h>
#include <stdint.h>

// ---------------------------------------------------------------------------
// GRU with pack_padded_sequence semantics on MI355X.
// Phase 1: pack weights to f16 (input-proj Wc for the big GEMM, plain f16
//          copies of W_h2h / W_h2o for the recurrence)
// Phase 2: MFMA f16 GEMM for hoisted input projections P = X @ Wc^T + bias
// Phase 3: persistent-weight multi-CU recurrence:
//          4 batch-groups x 16 neuron-slices = 64 blocks. Each block keeps
//          its 96 KB weight slice in LDS forever (zero per-step weight
//          traffic -- the old kernel streamed 1.5 MB/step from L2 per CU,
//          which was the 11.9 us/step ceiling). Per step the 16 blocks of a
//          group exchange h / g (16 KB each) through L3 via agent-scope
//          (L2-bypassing) atomics, synced by sequence-numbered flag counters.
// ---------------------------------------------------------------------------

typedef _Float16 h8_t __attribute__((ext_vector_type(8)));
typedef float    f4_t __attribute__((ext_vector_type(4)));
typedef unsigned long long u64;

#define NB   64
#define NT   2048
#define ND   512
#define NH   512
#define NROW (NB * NT)          // 131072
#define NCOL 1536               // 2H + H
#define NGRP 4                  // batch groups (16 rows each; lens sorted)
#define NSL  16                 // neuron slices (32 neurons each)
#define WPAD 520                // padded f16 row stride (512+8): kills the
                                // 16-way LDS bank conflict of stride-1024B rows

// workspace layout (bytes), all 16B aligned
static const size_t OFF_P   = 0;                                 // f16 [131072][1536]
static const size_t OFF_WC  = (size_t)NROW * NCOL * 2;           // f16 [1536][512]
static const size_t OFF_WHH = OFF_WC  + (size_t)1536 * 512 * 2;  // f16 [1024][512]
static const size_t OFF_WHO = OFF_WHH + (size_t)1024 * 512 * 2;  // f16 [512][512]
static const size_t OFF_CB  = OFF_WHO + (size_t)512 * 512 * 2;   // f32 [1536]
static const size_t OFF_HC  = OFF_CB  + 1536 * 4;                // f16 [64][512] h comm
static const size_t OFF_GC  = OFF_HC  + (size_t)NB * 512 * 2;    // f16 [64][512] g comm
static const size_t OFF_FL  = OFF_GC  + (size_t)NB * 512 * 2;    // u32 [2][NGRP][NT+1]
static const size_t FL_SZ   = (size_t)2 * NGRP * (NT + 1) * 4;

// ---------------------------------------------------------------------------
// Phase 1: weight/bias packing
// ---------------------------------------------------------------------------
__global__ void pack_kernel(const float* __restrict__ Wi2h, const float* __restrict__ bi2h,
                            const float* __restrict__ Wh2h, const float* __restrict__ bh2h,
                            const float* __restrict__ Wi2o, const float* __restrict__ bi2o,
                            const float* __restrict__ Wh2o, const float* __restrict__ bh2o,
                            _Float16* __restrict__ Wc, _Float16* __restrict__ Whh,
                            _Float16* __restrict__ Who, float* __restrict__ cbias)
{
    int id = blockIdx.x * 256 + threadIdx.x;
    if (id < 786432) {
        int n = id >> 9;
        float v = (n < 1024) ? Wi2h[id] : Wi2o[id - 524288];
        Wc[id] = (_Float16)v;
    } else if (id < 786432 + 524288) {
        int lid = id - 786432;
        Whh[lid] = (_Float16)Wh2h[lid];
    } else if (id < 786432 + 524288 + 262144) {
        int lid = id - 1310720;
        Who[lid] = (_Float16)Wh2o[lid];
    } else if (id < 1572864 + 1536) {
        int n = id - 1572864;
        cbias[n] = (n < 1024) ? (bi2h[n] + bh2h[n]) : (bi2o[n - 1024] + bh2o[n - 1024]);
    }
}

// ---------------------------------------------------------------------------
// Phase 2: P[row][n] = sum_k X[row][k] * Wc[n][k] + cbias[n], f16 out.
// (unchanged from previous round -- it is ~2% of runtime and verified)
// ---------------------------------------------------------------------------
__global__ void gemm_proj(const float* __restrict__ X, const _Float16* __restrict__ Wc,
                          const float* __restrict__ cbias, const int* __restrict__ lens,
                          _Float16* __restrict__ P)
{
    int bid  = blockIdx.x;
    int xcd  = bid & 7;
    int slot = bid >> 3;
    int nt   = slot % 12;
    int tyl  = slot / 12;
    int ty   = xcd * 128 + tyl;

    int b  = ty >> 4;
    int t0 = (ty << 7) & 2047;
    if (t0 >= lens[b]) return;

    int rowbase = ty << 7;
    int nbase   = nt << 7;

    __shared__ _Float16 As[128][40];
    __shared__ _Float16 Bs[128][40];

    int tid  = threadIdx.x;
    int lane = tid & 63, w = tid >> 6;
    int wm = w >> 1, wn = w & 1;
    int fr = lane & 15, quad = lane >> 4;

    f4_t acc[4][4] = {};

    int sr = tid >> 2;
    int sc = (tid & 3) << 3;

    for (int kc = 0; kc < 16; ++kc) {
        int k0 = kc << 5;
#pragma unroll
        for (int p = 0; p < 2; ++p) {
            int r = sr + p * 64;
            const float* asrc = X + (size_t)(rowbase + r) * 512 + k0 + sc;
            f4_t a0 = *(const f4_t*)asrc;
            f4_t a1 = *(const f4_t*)(asrc + 4);
            h8_t hv;
            hv[0] = (_Float16)a0[0]; hv[1] = (_Float16)a0[1];
            hv[2] = (_Float16)a0[2]; hv[3] = (_Float16)a0[3];
            hv[4] = (_Float16)a1[0]; hv[5] = (_Float16)a1[1];
            hv[6] = (_Float16)a1[2]; hv[7] = (_Float16)a1[3];
            *(h8_t*)&As[r][sc] = hv;
            *(h8_t*)&Bs[r][sc] = *(const h8_t*)(Wc + (size_t)(nbase + r) * 512 + k0 + sc);
        }
        __syncthreads();

        h8_t af[4], bf[4];
#pragma unroll
        for (int i = 0; i < 4; ++i) {
            af[i] = *(const h8_t*)&As[wm * 64 + i * 16 + fr][quad * 8];
            bf[i] = *(const h8_t*)&Bs[wn * 64 + i * 16 + fr][quad * 8];
        }
#pragma unroll
        for (int mi = 0; mi < 4; ++mi)
#pragma unroll
            for (int ni = 0; ni < 4; ++ni)
                acc[mi][ni] = __builtin_amdgcn_mfma_f32_16x16x32_f16(
                    af[mi], bf[ni], acc[mi][ni], 0, 0, 0);
        __syncthreads();
    }

#pragma unroll
    for (int ni = 0; ni < 4; ++ni) {
        int gcol = nbase + wn * 64 + ni * 16 + fr;
        float bias = cbias[gcol];
#pragma unroll
        for (int mi = 0; mi < 4; ++mi) {
            int grow0 = rowbase + wm * 64 + mi * 16 + quad * 4;
#pragma unroll
            for (int rg = 0; rg < 4; ++rg)
                P[(size_t)(grow0 + rg) * NCOL + gcol] = (_Float16)(acc[mi][ni][rg] + bias);
        }
    }
}

// ---------------------------------------------------------------------------
// Phase 3: persistent-weight recurrence.
// Block (g,s): batch rows g*16..g*16+15, neurons s*32..s*32+31.
// LDS holds the slice's weights forever; h/g cross-block exchange goes
// through L3 with agent-scope atomics + per-step flag counters.
// ---------------------------------------------------------------------------
__global__ __launch_bounds__(256)
void gru_rec(const _Float16* __restrict__ P,
             const _Float16* __restrict__ Whh,
             const _Float16* __restrict__ Who,
             const int* __restrict__ lens,
             float* __restrict__ out,
             _Float16* __restrict__ hcom,
             _Float16* __restrict__ gcom,
             unsigned int* __restrict__ flags)
{
    const int g    = blockIdx.x >> 4;
    const int s    = blockIdx.x & 15;
    const int tid  = threadIdx.x;
    const int lane = tid & 63;
    const int w    = tid >> 6;       // wave 0..3
    const int fr   = lane & 15;
    const int quad = lane >> 4;

    __shared__ _Float16 Wzr[64][WPAD];   // rows 0..31: z-slice of W_h2h; 32..63: r-slice
    __shared__ _Float16 Wso[32][WPAD];   // s-slice of W_h2o
    __shared__ _Float16 hst[16][WPAD];   // staged h (MFMA A operand)
    __shared__ _Float16 gst[16][WPAD];   // staged g
    __shared__ float    hloc[16][32];    // own-slice h, f32 (for g = h*sig(r))
    __shared__ _Float16 hout[16][32];    // own-slice h_new, f16 (comm push)
    __shared__ _Float16 gout[16][32];    // own-slice g, f16 (comm push)

    unsigned int* hflg = flags + g * (NT + 1);
    unsigned int* gflg = flags + (NGRP + g) * (NT + 1);

    // ---- one-time: stage this slice's recurrent weights into LDS ----
    for (int idx = tid; idx < 96 * 64; idx += 256) {
        int r = idx >> 6, ch = idx & 63;
        if (r < 64) {
            int grow = (r < 32) ? (s * 32 + r) : (512 + s * 32 + r - 32);
            *(uint4*)&Wzr[r][ch * 8] = ((const uint4*)(Whh + (size_t)grow * 512))[ch];
        } else {
            int grow = s * 32 + r - 64;
            *(uint4*)&Wso[r - 64][ch * 8] = ((const uint4*)(Who + (size_t)grow * 512))[ch];
        }
    }

    int    lrow[4];
    size_t pbase[4], obase[4];
    int    row_[4];
#pragma unroll
    for (int rg = 0; rg < 4; ++rg) {
        int row  = quad * 4 + rg;
        row_[rg] = row;
        int brow = g * 16 + row;
        lrow[rg]  = lens[brow];
        pbase[rg] = (size_t)brow * NT * NCOL;
        obase[rg] = (size_t)brow * NT * NH;
    }
    int steps = 0;
    for (int i = 0; i < 16; ++i) { int l = lens[g * 16 + i]; if (l > steps) steps = l; }

    float hreg[4] = {0.f, 0.f, 0.f, 0.f};
    float zreg[4] = {0.f, 0.f, 0.f, 0.f};

    const int lcol01 = w * 16 + fr;        // waves 0,1: local/output column
    const int gcol01 = s * 32 + lcol01;
    const int rl23   = (w - 2) * 16 + fr;  // waves 2,3: local r column
    const int pcolr  = 512 + s * 32 + rl23;

    // ---- h(-1) = 0: init own slice, publish, arrive at hflg[0] ----
    if (w < 2) {
#pragma unroll
        for (int rg = 0; rg < 4; ++rg) hloc[row_[rg]][lcol01] = 0.f;
    }
    if (tid < 128) {
        int r = tid >> 3, c = tid & 7;
        __hip_atomic_store((u64*)(hcom + (size_t)(g * 16 + r) * 512 + s * 32) + c,
                           0ull, __ATOMIC_RELAXED, __HIP_MEMORY_SCOPE_AGENT);
    }
    asm volatile("s_waitcnt vmcnt(0)" ::: "memory");
    __syncthreads();
    if (tid == 0)
        __hip_atomic_fetch_add(&hflg[0], 1u, __ATOMIC_RELEASE, __HIP_MEMORY_SCOPE_AGENT);

    for (int t = 0; t < steps; ++t) {
        // ================= phase A: zr preact, g = h*sig(r) =================
        if (tid == 0)
            while (__hip_atomic_load(&hflg[t], __ATOMIC_RELAXED,
                                     __HIP_MEMORY_SCOPE_AGENT) < (unsigned)NSL)
                __builtin_amdgcn_s_sleep(1);
        __syncthreads();

        // issue this step's P loads early (consumed after the MFMAs)
        _Float16 pzv[4], pov[4];
        const size_t tofs = (size_t)t * NCOL;
        if (w < 2) {
#pragma unroll
            for (int rg = 0; rg < 4; ++rg) {
                pzv[rg] = P[pbase[rg] + tofs + gcol01];
                pov[rg] = P[pbase[rg] + tofs + 1024 + gcol01];
            }
        } else {
#pragma unroll
            for (int rg = 0; rg < 4; ++rg)
                pzv[rg] = P[pbase[rg] + tofs + pcolr];
        }

        // stage full h (L2-bypassing agent loads) -> LDS
#pragma unroll
        for (int i = 0; i < 8; ++i) {
            int idx = tid + i * 256;
            int r = idx >> 7, c4 = idx & 127;
            u64 v = __hip_atomic_load((u64*)(hcom + (size_t)(g * 16 + r) * 512) + c4,
                                      __ATOMIC_RELAXED, __HIP_MEMORY_SCOPE_AGENT);
            *(u64*)&hst[r][c4 * 4] = v;
        }
        __syncthreads();

        // y[16 rows][16 cols] per wave: waves 0,1 -> z tile, waves 2,3 -> r tile
        f4_t a0 = {0.f, 0.f, 0.f, 0.f}, a1 = {0.f, 0.f, 0.f, 0.f};
#pragma unroll
        for (int k = 0; k < 16; k += 2) {
            h8_t af0 = *(const h8_t*)&hst[fr][k * 32 + quad * 8];
            h8_t bf0 = *(const h8_t*)&Wzr[w * 16 + fr][k * 32 + quad * 8];
            a0 = __builtin_amdgcn_mfma_f32_16x16x32_f16(af0, bf0, a0, 0, 0, 0);
            h8_t af1 = *(const h8_t*)&hst[fr][(k + 1) * 32 + quad * 8];
            h8_t bf1 = *(const h8_t*)&Wzr[w * 16 + fr][(k + 1) * 32 + quad * 8];
            a1 = __builtin_amdgcn_mfma_f32_16x16x32_f16(af1, bf1, a1, 0, 0, 0);
        }

        if (w < 2) {
#pragma unroll
            for (int rg = 0; rg < 4; ++rg)
                zreg[rg] = a0[rg] + a1[rg] + (float)pzv[rg];
        } else {
#pragma unroll
            for (int rg = 0; rg < 4; ++rg) {
                float rv = a0[rg] + a1[rg] + (float)pzv[rg];
                float sg = 1.f / (1.f + __expf(-rv));
                gout[row_[rg]][rl23] = (_Float16)(hloc[row_[rg]][rl23] * sg);
            }
        }
        __syncthreads();

        // publish g slice
        if (tid < 128) {
            int r = tid >> 3, c = tid & 7;
            u64 v = *(const u64*)&gout[r][c * 4];
            __hip_atomic_store((u64*)(gcom + (size_t)(g * 16 + r) * 512 + s * 32) + c,
                               v, __ATOMIC_RELAXED, __HIP_MEMORY_SCOPE_AGENT);
        }
        asm volatile("s_waitcnt vmcnt(0)" ::: "memory");
        __syncthreads();
        if (tid == 0)
            __hip_atomic_fetch_add(&gflg[t], 1u, __ATOMIC_RELEASE, __HIP_MEMORY_SCOPE_AGENT);

        // ================= phase B: s preact, h update =================
        if (tid == 0)
            while (__hip_atomic_load(&gflg[t], __ATOMIC_RELAXED,
                                     __HIP_MEMORY_SCOPE_AGENT) < (unsigned)NSL)
                __builtin_amdgcn_s_sleep(1);
        __syncthreads();

#pragma unroll
        for (int i = 0; i < 8; ++i) {
            int idx = tid + i * 256;
            int r = idx >> 7, c4 = idx & 127;
            u64 v = __hip_atomic_load((u64*)(gcom + (size_t)(g * 16 + r) * 512) + c4,
                                      __ATOMIC_RELAXED, __HIP_MEMORY_SCOPE_AGENT);
            *(u64*)&gst[r][c4 * 4] = v;
        }
        __syncthreads();

        if (w < 2) {
            f4_t b0 = {0.f, 0.f, 0.f, 0.f}, b1 = {0.f, 0.f, 0.f, 0.f};
#pragma unroll
            for (int k = 0; k < 16; k += 2) {
                h8_t af0 = *(const h8_t*)&gst[fr][k * 32 + quad * 8];
                h8_t bf0 = *(const h8_t*)&Wso[w * 16 + fr][k * 32 + quad * 8];
                b0 = __builtin_amdgcn_mfma_f32_16x16x32_f16(af0, bf0, b0, 0, 0, 0);
                h8_t af1 = *(const h8_t*)&gst[fr][(k + 1) * 32 + quad * 8];
                h8_t bf1 = *(const h8_t*)&Wso[w * 16 + fr][(k + 1) * 32 + quad * 8];
                b1 = __builtin_amdgcn_mfma_f32_16x16x32_f16(af1, bf1, b1, 0, 0, 0);
            }
#pragma unroll
            for (int rg = 0; rg < 4; ++rg) {
                float sv = b0[rg] + b1[rg] + (float)pov[rg];
                float zs = 1.f / (1.f + __expf(-zreg[rg]));
                float th = 1.f - 2.f / (__expf(2.f * sv) + 1.f);
                float hn = (1.f - zs) * hreg[rg] + zs * th;
                bool act  = t < lrow[rg];
                float hc  = act ? hn : hreg[rg];          // freeze finished rows
                out[obase[rg] + (size_t)t * NH + gcol01] = act ? hn : 0.f;
                hreg[rg] = hc;
                hloc[row_[rg]][lcol01] = hc;
                hout[row_[rg]][lcol01] = (_Float16)hc;
            }
        }
        __syncthreads();

        // publish h slice
        if (tid < 128) {
            int r = tid >> 3, c = tid & 7;
            u64 v = *(const u64*)&hout[r][c * 4];
            __hip_atomic_store((u64*)(hcom + (size_t)(g * 16 + r) * 512 + s * 32) + c,
                               v, __ATOMIC_RELAXED, __HIP_MEMORY_SCOPE_AGENT);
        }
        asm volatile("s_waitcnt vmcnt(0)" ::: "memory");
        __syncthreads();
        if (tid == 0)
            __hip_atomic_fetch_add(&hflg[t + 1], 1u, __ATOMIC_RELEASE, __HIP_MEMORY_SCOPE_AGENT);
    }

    // final hidden state (frozen at t = len)
    if (w < 2) {
#pragma unroll
        for (int rg = 0; rg < 4; ++rg)
            out[(size_t)NB * NT * NH + (size_t)(g * 16 + row_[rg]) * NH + gcol01] = hreg[rg];
    }

    // zero-fill out[t in [steps, NT)) for this block's row (= g*16 + s);
    // rows finished before `steps` were zeroed in-loop by the masked store.
    {
        long n4 = (long)(NT - steps) * 128;
        f4_t* dst = (f4_t*)(out + (size_t)(g * 16 + s) * NT * NH + (size_t)steps * NH);
        f4_t z = {0.f, 0.f, 0.f, 0.f};
        for (long i = tid; i < n4; i += 256) dst[i] = z;
    }
}

// ---------------------------------------------------------------------------
extern "C" void kernel_launch(void* const* d_in, const int* in_sizes, int n_in,
                              void* d_out, int out_size, void* d_ws, size_t ws_size,
                              hipStream_t stream)
{
    const float* X    = (const float*)d_in[0];
    const int*  lens  = (const int*)d_in[1];
    const float* Wi2h = (const float*)d_in[2];
    const float* bi2h = (const float*)d_in[3];
    const float* Wh2h = (const float*)d_in[4];
    const float* bh2h = (const float*)d_in[5];
    const float* Wi2o = (const float*)d_in[6];
    const float* bi2o = (const float*)d_in[7];
    const float* Wh2o = (const float*)d_in[8];
    const float* bh2o = (const float*)d_in[9];

    char* ws = (char*)d_ws;
    _Float16* P    = (_Float16*)(ws + OFF_P);
    _Float16* Wc   = (_Float16*)(ws + OFF_WC);
    _Float16* Whh  = (_Float16*)(ws + OFF_WHH);
    _Float16* Who  = (_Float16*)(ws + OFF_WHO);
    float*    cb   = (float*)(ws + OFF_CB);
    _Float16* hcom = (_Float16*)(ws + OFF_HC);
    _Float16* gcom = (_Float16*)(ws + OFF_GC);
    unsigned int* flags = (unsigned int*)(ws + OFF_FL);
    float* out = (float*)d_out;

    // flags must be zero every launch (sequence-numbered barrier counters)
    hipMemsetAsync(ws + OFF_FL, 0, FL_SZ, stream);

    pack_kernel<<<6150, 256, 0, stream>>>(Wi2h, bi2h, Wh2h, bh2h,
                                          Wi2o, bi2o, Wh2o, bh2o,
                                          Wc, Whh, Who, cb);
    gemm_proj<<<12288, 256, 0, stream>>>(X, Wc, cb, lens, P);
    gru_rec<<<NGRP * NSL, 256, 0, stream>>>(P, Whh, Who, lens, out, hcom, gcom, flags);
}

// Round 2
// 17296.233 us; speedup vs baseline: 1.4396x; 1.1993x over previous
//
#include <hip/hip_runtime.h>
#include <stdint.h>

// ---------------------------------------------------------------------------
// GRU with pack_padded_sequence semantics on MI355X.
// Phase 1: pack weights to f16
// Phase 2: MFMA f16 GEMM for hoisted input projections P = X @ Wc^T + bias
// Phase 3: persistent-weight multi-CU recurrence:
//          4 batch-groups x 16 neuron-slices = 64 blocks; weight slices live
//          in LDS forever; per-step h/g exchange through L3 via agent-scope
//          relaxed atomics. Round-2 changes (sync-latency chain surgery):
//            - per-slice flag words (64B apart), plain relaxed stores
//              (kills the 16-way atomic-RMW serialization on one line and
//               the RELEASE cache-maintenance ops)
//            - wave-parallel poll: 16 lanes watch 16 flags, __all() detect
//            - g/h published directly from computing waves' registers
//              (removes 2 LDS round-trips + 2 __syncthreads per step)
//            - P loads issued before the flag wait (latency hidden)
// ---------------------------------------------------------------------------

typedef _Float16 h8_t __attribute__((ext_vector_type(8)));
typedef float    f4_t __attribute__((ext_vector_type(4)));
typedef unsigned long long u64;

#define NB   64
#define NT   2048
#define ND   512
#define NH   512
#define NROW (NB * NT)          // 131072
#define NCOL 1536               // 2H + H
#define NGRP 4                  // batch groups (16 rows each; lens sorted)
#define NSL  16                 // neuron slices (32 neurons each)
#define WPAD 520                // padded f16 row stride

// workspace layout (bytes), all 16B aligned
static const size_t OFF_P   = 0;                                 // f16 [131072][1536]
static const size_t OFF_WC  = (size_t)NROW * NCOL * 2;           // f16 [1536][512]
static const size_t OFF_WHH = OFF_WC  + (size_t)1536 * 512 * 2;  // f16 [1024][512]
static const size_t OFF_WHO = OFF_WHH + (size_t)1024 * 512 * 2;  // f16 [512][512]
static const size_t OFF_CB  = OFF_WHO + (size_t)512 * 512 * 2;   // f32 [1536]
static const size_t OFF_HC  = OFF_CB  + 1536 * 4;                // f16 [64][512] h comm
static const size_t OFF_GC  = OFF_HC  + (size_t)NB * 512 * 2;    // f16 [64][512] g comm
static const size_t OFF_FL  = OFF_GC  + (size_t)NB * 512 * 2;    // u32 flags, 64B/slot
// flag slot (phase p, group g, slice s) = u32 index ((p*4+g)*16+s)*16
static const size_t FL_SZ   = (size_t)2 * NGRP * NSL * 16 * 4;   // 8 KiB

// ---------------------------------------------------------------------------
// Phase 1: weight/bias packing
// ---------------------------------------------------------------------------
__global__ void pack_kernel(const float* __restrict__ Wi2h, const float* __restrict__ bi2h,
                            const float* __restrict__ Wh2h, const float* __restrict__ bh2h,
                            const float* __restrict__ Wi2o, const float* __restrict__ bi2o,
                            const float* __restrict__ Wh2o, const float* __restrict__ bh2o,
                            _Float16* __restrict__ Wc, _Float16* __restrict__ Whh,
                            _Float16* __restrict__ Who, float* __restrict__ cbias)
{
    int id = blockIdx.x * 256 + threadIdx.x;
    if (id < 786432) {
        int n = id >> 9;
        float v = (n < 1024) ? Wi2h[id] : Wi2o[id - 524288];
        Wc[id] = (_Float16)v;
    } else if (id < 786432 + 524288) {
        int lid = id - 786432;
        Whh[lid] = (_Float16)Wh2h[lid];
    } else if (id < 786432 + 524288 + 262144) {
        int lid = id - 1310720;
        Who[lid] = (_Float16)Wh2o[lid];
    } else if (id < 1572864 + 1536) {
        int n = id - 1572864;
        cbias[n] = (n < 1024) ? (bi2h[n] + bh2h[n]) : (bi2o[n - 1024] + bh2o[n - 1024]);
    }
}

// ---------------------------------------------------------------------------
// Phase 2: P[row][n] = sum_k X[row][k] * Wc[n][k] + cbias[n], f16 out.
// (unchanged -- ~2% of runtime, verified)
// ---------------------------------------------------------------------------
__global__ void gemm_proj(const float* __restrict__ X, const _Float16* __restrict__ Wc,
                          const float* __restrict__ cbias, const int* __restrict__ lens,
                          _Float16* __restrict__ P)
{
    int bid  = blockIdx.x;
    int xcd  = bid & 7;
    int slot = bid >> 3;
    int nt   = slot % 12;
    int tyl  = slot / 12;
    int ty   = xcd * 128 + tyl;

    int b  = ty >> 4;
    int t0 = (ty << 7) & 2047;
    if (t0 >= lens[b]) return;

    int rowbase = ty << 7;
    int nbase   = nt << 7;

    __shared__ _Float16 As[128][40];
    __shared__ _Float16 Bs[128][40];

    int tid  = threadIdx.x;
    int lane = tid & 63, w = tid >> 6;
    int wm = w >> 1, wn = w & 1;
    int fr = lane & 15, quad = lane >> 4;

    f4_t acc[4][4] = {};

    int sr = tid >> 2;
    int sc = (tid & 3) << 3;

    for (int kc = 0; kc < 16; ++kc) {
        int k0 = kc << 5;
#pragma unroll
        for (int p = 0; p < 2; ++p) {
            int r = sr + p * 64;
            const float* asrc = X + (size_t)(rowbase + r) * 512 + k0 + sc;
            f4_t a0 = *(const f4_t*)asrc;
            f4_t a1 = *(const f4_t*)(asrc + 4);
            h8_t hv;
            hv[0] = (_Float16)a0[0]; hv[1] = (_Float16)a0[1];
            hv[2] = (_Float16)a0[2]; hv[3] = (_Float16)a0[3];
            hv[4] = (_Float16)a1[0]; hv[5] = (_Float16)a1[1];
            hv[6] = (_Float16)a1[2]; hv[7] = (_Float16)a1[3];
            *(h8_t*)&As[r][sc] = hv;
            *(h8_t*)&Bs[r][sc] = *(const h8_t*)(Wc + (size_t)(nbase + r) * 512 + k0 + sc);
        }
        __syncthreads();

        h8_t af[4], bf[4];
#pragma unroll
        for (int i = 0; i < 4; ++i) {
            af[i] = *(const h8_t*)&As[wm * 64 + i * 16 + fr][quad * 8];
            bf[i] = *(const h8_t*)&Bs[wn * 64 + i * 16 + fr][quad * 8];
        }
#pragma unroll
        for (int mi = 0; mi < 4; ++mi)
#pragma unroll
            for (int ni = 0; ni < 4; ++ni)
                acc[mi][ni] = __builtin_amdgcn_mfma_f32_16x16x32_f16(
                    af[mi], bf[ni], acc[mi][ni], 0, 0, 0);
        __syncthreads();
    }

#pragma unroll
    for (int ni = 0; ni < 4; ++ni) {
        int gcol = nbase + wn * 64 + ni * 16 + fr;
        float bias = cbias[gcol];
#pragma unroll
        for (int mi = 0; mi < 4; ++mi) {
            int grow0 = rowbase + wm * 64 + mi * 16 + quad * 4;
#pragma unroll
            for (int rg = 0; rg < 4; ++rg)
                P[(size_t)(grow0 + rg) * NCOL + gcol] = (_Float16)(acc[mi][ni][rg] + bias);
        }
    }
}

// ---------------------------------------------------------------------------
// Phase 3: persistent-weight recurrence (see header comment).
// ---------------------------------------------------------------------------
__global__ __launch_bounds__(256)
void gru_rec(const _Float16* __restrict__ P,
             const _Float16* __restrict__ Whh,
             const _Float16* __restrict__ Who,
             const int* __restrict__ lens,
             float* __restrict__ out,
             _Float16* __restrict__ hcom,
             _Float16* __restrict__ gcom,
             unsigned int* __restrict__ flags)
{
    const int g    = blockIdx.x >> 4;
    const int s    = blockIdx.x & 15;
    const int tid  = threadIdx.x;
    const int lane = tid & 63;
    const int w    = tid >> 6;       // wave 0..3
    const int fr   = lane & 15;
    const int quad = lane >> 4;

    __shared__ _Float16 Wzr[64][WPAD];   // rows 0..31: z-slice of W_h2h; 32..63: r-slice
    __shared__ _Float16 Wso[32][WPAD];   // s-slice of W_h2o
    __shared__ _Float16 hst[16][WPAD];   // staged h (MFMA A operand)
    __shared__ _Float16 gst[16][WPAD];   // staged g
    __shared__ float    hloc[16][32];    // own-slice h, f32 (for g = h*sig(r))

    // per-(group) flag bases; each slice's flag is a u32 64B apart
    unsigned int* hfl = flags + (size_t)g * 256;            // phase 0
    unsigned int* gfl = flags + (size_t)(NGRP + g) * 256;   // phase 1

    // ---- one-time: stage this slice's recurrent weights into LDS ----
    for (int idx = tid; idx < 96 * 64; idx += 256) {
        int r = idx >> 6, ch = idx & 63;
        if (r < 64) {
            int grow = (r < 32) ? (s * 32 + r) : (512 + s * 32 + r - 32);
            *(uint4*)&Wzr[r][ch * 8] = ((const uint4*)(Whh + (size_t)grow * 512))[ch];
        } else {
            int grow = s * 32 + r - 64;
            *(uint4*)&Wso[r - 64][ch * 8] = ((const uint4*)(Who + (size_t)grow * 512))[ch];
        }
    }

    int    lrow[4];
    size_t pbase[4], obase[4];
    int    row_[4];
#pragma unroll
    for (int rg = 0; rg < 4; ++rg) {
        int row  = quad * 4 + rg;
        row_[rg] = row;
        int brow = g * 16 + row;
        lrow[rg]  = lens[brow];
        pbase[rg] = (size_t)brow * NT * NCOL;
        obase[rg] = (size_t)brow * NT * NH;
    }
    int steps = 0;
    for (int i = 0; i < 16; ++i) { int l = lens[g * 16 + i]; if (l > steps) steps = l; }

    float hreg[4] = {0.f, 0.f, 0.f, 0.f};
    float zreg[4] = {0.f, 0.f, 0.f, 0.f};

    const int lcol01 = w * 16 + fr;        // waves 0,1: local/output column
    const int gcol01 = s * 32 + lcol01;
    const int rl23   = (w - 2) * 16 + fr;  // waves 2,3: local r column
    const int pcolr  = 512 + s * 32 + rl23;

    // ---- h(-1) = 0: init own slice, publish, set hflag = 1 ----
    if (w < 2) {
#pragma unroll
        for (int rg = 0; rg < 4; ++rg) hloc[row_[rg]][lcol01] = 0.f;
    }
    if (tid < 128) {
        int r = tid >> 3, c = tid & 7;
        __hip_atomic_store((u64*)(hcom + (size_t)(g * 16 + r) * 512 + s * 32) + c,
                           0ull, __ATOMIC_RELAXED, __HIP_MEMORY_SCOPE_AGENT);
    }
    asm volatile("s_waitcnt vmcnt(0)" ::: "memory");
    __syncthreads();
    if (tid == 0)
        __hip_atomic_store(&hfl[s * 16], 1u, __ATOMIC_RELAXED, __HIP_MEMORY_SCOPE_AGENT);

    for (int t = 0; t < steps; ++t) {
        const unsigned need = (unsigned)(t + 1);
        const size_t tofs = (size_t)t * NCOL;

        // issue this step's P loads before the flag wait (latency hidden)
        _Float16 pzv[4], pov[4];
        if (w < 2) {
#pragma unroll
            for (int rg = 0; rg < 4; ++rg) {
                pzv[rg] = P[pbase[rg] + tofs + gcol01];
                pov[rg] = P[pbase[rg] + tofs + 1024 + gcol01];
            }
        } else {
#pragma unroll
            for (int rg = 0; rg < 4; ++rg)
                pzv[rg] = P[pbase[rg] + tofs + pcolr];
        }

        // ================= phase A: zr preact, g = h*sig(r) =================
        // wave 0: 16 lanes each watch one slice's h-flag
        if (tid < 64) {
            for (;;) {
                unsigned v = __hip_atomic_load(&hfl[(lane & 15) * 16],
                                               __ATOMIC_RELAXED, __HIP_MEMORY_SCOPE_AGENT);
                if (__all(v >= need)) break;
                __builtin_amdgcn_s_sleep(1);
            }
        }
        __syncthreads();

        // stage full h (agent loads, L2-bypassing) -> LDS
#pragma unroll
        for (int i = 0; i < 8; ++i) {
            int idx = tid + i * 256;
            int r = idx >> 7, c4 = idx & 127;
            u64 v = __hip_atomic_load((u64*)(hcom + (size_t)(g * 16 + r) * 512) + c4,
                                      __ATOMIC_RELAXED, __HIP_MEMORY_SCOPE_AGENT);
            *(u64*)&hst[r][c4 * 4] = v;
        }
        __syncthreads();

        // y[16 rows][16 cols] per wave: waves 0,1 -> z tile, waves 2,3 -> r tile
        f4_t a0 = {0.f, 0.f, 0.f, 0.f}, a1 = {0.f, 0.f, 0.f, 0.f};
#pragma unroll
        for (int k = 0; k < 16; k += 2) {
            h8_t af0 = *(const h8_t*)&hst[fr][k * 32 + quad * 8];
            h8_t bf0 = *(const h8_t*)&Wzr[w * 16 + fr][k * 32 + quad * 8];
            a0 = __builtin_amdgcn_mfma_f32_16x16x32_f16(af0, bf0, a0, 0, 0, 0);
            h8_t af1 = *(const h8_t*)&hst[fr][(k + 1) * 32 + quad * 8];
            h8_t bf1 = *(const h8_t*)&Wzr[w * 16 + fr][(k + 1) * 32 + quad * 8];
            a1 = __builtin_amdgcn_mfma_f32_16x16x32_f16(af1, bf1, a1, 0, 0, 0);
        }

        if (w < 2) {
#pragma unroll
            for (int rg = 0; rg < 4; ++rg)
                zreg[rg] = a0[rg] + a1[rg] + (float)pzv[rg];
        } else {
            // compute g and publish straight from registers (no LDS round-trip)
#pragma unroll
            for (int rg = 0; rg < 4; ++rg) {
                float rv = a0[rg] + a1[rg] + (float)pzv[rg];
                float sg = 1.f / (1.f + __expf(-rv));
                _Float16 gv = (_Float16)(hloc[row_[rg]][rl23] * sg);
                __hip_atomic_store((unsigned short*)(gcom +
                        (size_t)(g * 16 + row_[rg]) * 512 + s * 32 + rl23),
                    *(unsigned short*)&gv, __ATOMIC_RELAXED, __HIP_MEMORY_SCOPE_AGENT);
            }
        }
        asm volatile("s_waitcnt vmcnt(0)" ::: "memory");
        __syncthreads();
        if (tid == 0)
            __hip_atomic_store(&gfl[s * 16], need, __ATOMIC_RELAXED, __HIP_MEMORY_SCOPE_AGENT);

        // ================= phase B: s preact, h update =================
        if (tid < 64) {
            for (;;) {
                unsigned v = __hip_atomic_load(&gfl[(lane & 15) * 16],
                                               __ATOMIC_RELAXED, __HIP_MEMORY_SCOPE_AGENT);
                if (__all(v >= need)) break;
                __builtin_amdgcn_s_sleep(1);
            }
        }
        __syncthreads();

#pragma unroll
        for (int i = 0; i < 8; ++i) {
            int idx = tid + i * 256;
            int r = idx >> 7, c4 = idx & 127;
            u64 v = __hip_atomic_load((u64*)(gcom + (size_t)(g * 16 + r) * 512) + c4,
                                      __ATOMIC_RELAXED, __HIP_MEMORY_SCOPE_AGENT);
            *(u64*)&gst[r][c4 * 4] = v;
        }
        __syncthreads();

        if (w < 2) {
            f4_t b0 = {0.f, 0.f, 0.f, 0.f}, b1 = {0.f, 0.f, 0.f, 0.f};
#pragma unroll
            for (int k = 0; k < 16; k += 2) {
                h8_t af0 = *(const h8_t*)&gst[fr][k * 32 + quad * 8];
                h8_t bf0 = *(const h8_t*)&Wso[w * 16 + fr][k * 32 + quad * 8];
                b0 = __builtin_amdgcn_mfma_f32_16x16x32_f16(af0, bf0, b0, 0, 0, 0);
                h8_t af1 = *(const h8_t*)&gst[fr][(k + 1) * 32 + quad * 8];
                h8_t bf1 = *(const h8_t*)&Wso[w * 16 + fr][(k + 1) * 32 + quad * 8];
                b1 = __builtin_amdgcn_mfma_f32_16x16x32_f16(af1, bf1, b1, 0, 0, 0);
            }
#pragma unroll
            for (int rg = 0; rg < 4; ++rg) {
                float sv = b0[rg] + b1[rg] + (float)pov[rg];
                float zs = 1.f / (1.f + __expf(-zreg[rg]));
                float th = 1.f - 2.f / (__expf(2.f * sv) + 1.f);
                float hn = (1.f - zs) * hreg[rg] + zs * th;
                bool act  = t < lrow[rg];
                float hc  = act ? hn : hreg[rg];          // freeze finished rows
                out[obase[rg] + (size_t)t * NH + gcol01] = act ? hn : 0.f;
                hreg[rg] = hc;
                hloc[row_[rg]][lcol01] = hc;
                _Float16 hv = (_Float16)hc;
                __hip_atomic_store((unsigned short*)(hcom +
                        (size_t)(g * 16 + row_[rg]) * 512 + gcol01),
                    *(unsigned short*)&hv, __ATOMIC_RELAXED, __HIP_MEMORY_SCOPE_AGENT);
            }
        }
        asm volatile("s_waitcnt vmcnt(0)" ::: "memory");
        __syncthreads();
        if (tid == 0)
            __hip_atomic_store(&hfl[s * 16], need + 1, __ATOMIC_RELAXED, __HIP_MEMORY_SCOPE_AGENT);
    }

    // final hidden state (frozen at t = len)
    if (w < 2) {
#pragma unroll
        for (int rg = 0; rg < 4; ++rg)
            out[(size_t)NB * NT * NH + (size_t)(g * 16 + row_[rg]) * NH + gcol01] = hreg[rg];
    }

    // zero-fill out[t in [steps, NT)) for this block's row (= g*16 + s);
    // rows finished before `steps` were zeroed in-loop by the masked store.
    {
        long n4 = (long)(NT - steps) * 128;
        f4_t* dst = (f4_t*)(out + (size_t)(g * 16 + s) * NT * NH + (size_t)steps * NH);
        f4_t z = {0.f, 0.f, 0.f, 0.f};
        for (long i = tid; i < n4; i += 256) dst[i] = z;
    }
}

// ---------------------------------------------------------------------------
extern "C" void kernel_launch(void* const* d_in, const int* in_sizes, int n_in,
                              void* d_out, int out_size, void* d_ws, size_t ws_size,
                              hipStream_t stream)
{
    const float* X    = (const float*)d_in[0];
    const int*  lens  = (const int*)d_in[1];
    const float* Wi2h = (const float*)d_in[2];
    const float* bi2h = (const float*)d_in[3];
    const float* Wh2h = (const float*)d_in[4];
    const float* bh2h = (const float*)d_in[5];
    const float* Wi2o = (const float*)d_in[6];
    const float* bi2o = (const float*)d_in[7];
    const float* Wh2o = (const float*)d_in[8];
    const float* bh2o = (const float*)d_in[9];

    char* ws = (char*)d_ws;
    _Float16* P    = (_Float16*)(ws + OFF_P);
    _Float16* Wc   = (_Float16*)(ws + OFF_WC);
    _Float16* Whh  = (_Float16*)(ws + OFF_WHH);
    _Float16* Who  = (_Float16*)(ws + OFF_WHO);
    float*    cb   = (float*)(ws + OFF_CB);
    _Float16* hcom = (_Float16*)(ws + OFF_HC);
    _Float16* gcom = (_Float16*)(ws + OFF_GC);
    unsigned int* flags = (unsigned int*)(ws + OFF_FL);
    float* out = (float*)d_out;

    // flags must be zero every launch (monotone per-slice step counters)
    hipMemsetAsync(ws + OFF_FL, 0, FL_SZ, stream);

    pack_kernel<<<6150, 256, 0, stream>>>(Wi2h, bi2h, Wh2h, bh2h,
                                          Wi2o, bi2o, Wh2o, bh2o,
                                          Wc, Whh, Who, cb);
    gemm_proj<<<12288, 256, 0, stream>>>(X, Wc, cb, lens, P);
    gru_rec<<<NGRP * NSL, 256, 0, stream>>>(P, Whh, Who, lens, out, hcom, gcom, flags);
}